// Round 3
// baseline (127.823 us; speedup 1.0000x reference)
//
#include <hip/hip_runtime.h>

// MaskPatchClassificationHead — B=4, P=256, F=512
// loss = KL(dist || softmax(x x^T / tau)) batchmean, x = normalize(inputs@W^T + b)
// SINGLE fused kernel, 256 blocks x 256 thr (1 block/CU):
//   phase 1: fc GEMM K-split2 (64x64 tile, 4x4 micro, dbuf LDS) + label sigs
//            -> per-block release flag (poison-proof 64-bit magic)
//   phase 2: score h h^T K-split4 (64x64, 4x4, dbuf) — spins on its 8 fc
//            producer flags (fine-grained overlap), writes Sp + diag dn,
//            releases its own flag
//   phase 3: loss — waits all 256 score flags (transitively covers sig/dn),
//            wave-per-row softmax/KL, done-counter finalize
// Cross-XCD coherence: producer __syncthreads + __threadfence (L2 wb) +
// agent release-store; consumer relaxed spin + __threadfence (L1/L2 inv).

#define INV_TAU (1.0f / 0.07f)
#define EPSC 1e-5f

constexpr int Bz = 4;
constexpr int Pn = 256;
constexpr int Fdim = 512;
constexpr int Mrows = Bz * Pn;                       // 1024
constexpr size_t HP_STRIDE = (size_t)Mrows * Fdim;   // per fc K-half partial
constexpr size_t SP_STRIDE = (size_t)Bz * Pn * Pn;   // per score K-quarter partial

__device__ __forceinline__ unsigned long long FLAG_MAGIC(int i) {
  // hi32 != lo32 for every slot => no byte- or dword-repeated poison collides
  return 0x5AFEC0DE00000000ULL + (unsigned long long)i;
}

// Butterfly reductions: result valid in ALL lanes.
__device__ __forceinline__ float wave_sum(float v) {
  #pragma unroll
  for (int o = 32; o > 0; o >>= 1) v += __shfl_xor(v, o, 64);
  return v;
}
__device__ __forceinline__ float wave_max(float v) {
  #pragma unroll
  for (int o = 32; o > 0; o >>= 1) v = fmaxf(v, __shfl_xor(v, o, 64));
  return v;
}
__device__ __forceinline__ unsigned long long mix64(unsigned long long z) {
  z ^= z >> 33; z *= 0xff51afd7ed558ccdULL;
  z ^= z >> 33; z *= 0xc4ceb9fe1a85ec53ULL;
  z ^= z >> 33; return z;
}

__global__ __launch_bounds__(256) void fused(const float* __restrict__ A,
                                             const float* __restrict__ W,
                                             const float* __restrict__ bias,
                                             const float* __restrict__ labels,
                                             float* __restrict__ hp,
                                             ulonglong2* __restrict__ sig,
                                             float* __restrict__ Sp,
                                             float* __restrict__ dn,
                                             unsigned long long* __restrict__ fcflag,
                                             unsigned long long* __restrict__ scflag,
                                             float* __restrict__ acc,
                                             unsigned int* __restrict__ done,
                                             float* __restrict__ out) {
  const int t = threadIdx.x;
  const int bid = blockIdx.x;
  if (bid == 0 && t == 0) { acc[0] = 0.0f; done[0] = 0u; }

  __shared__ float Ash[2][32][68];  // [buf][k][m] — reused by phases 1 & 2
  __shared__ float Bsh[2][32][68];  // [buf][k][n]
  __shared__ float invn[256];
  __shared__ float red[4];

  // ================= phase 1: fc partial GEMM + label sigs =================
  {
    // --- label signatures: 4 rows per block, one 64-lane group per row
    {
      const int g = t >> 6, lane = t & 63;
      const int row = bid * 4 + g;
      const uint4* l4 = (const uint4*)(labels + (size_t)row * Fdim);
      unsigned long long h1 = 0, h2 = 0;
      #pragma unroll
      for (int c = lane; c < Fdim / 4; c += 64) {
        uint4 wv = l4[c];
        unsigned long long w01 = ((unsigned long long)wv.y << 32) | wv.x;
        unsigned long long w23 = ((unsigned long long)wv.w << 32) | wv.z;
        unsigned long long idx = (unsigned long long)c;
        h1 ^= mix64(w01 + idx * 0x9E3779B97F4A7C15ULL + 0x0123456789ABCDEFULL);
        h1 ^= mix64(w23 + idx * 0xC2B2AE3D27D4EB4FULL + 1ULL);
        h2 ^= mix64(w01 ^ (idx * 0x165667B19E3779F9ULL + 7ULL));
        h2 ^= mix64(w23 ^ (idx * 0x27D4EB2F165667C5ULL + 13ULL));
      }
      #pragma unroll
      for (int o = 32; o > 0; o >>= 1) {
        h1 ^= __shfl_down(h1, o, 64);
        h2 ^= __shfl_down(h2, o, 64);
      }
      if (lane == 0) { sig[row].x = h1; sig[row].y = h2; }
    }

    // --- fc GEMM: bid = mi + 16*ni + 128*z  (old grid (16,8,2))
    const int mi = bid & 15, ni = (bid >> 4) & 7, z = bid >> 7;
    const int m0 = mi * 64, n0 = ni * 64;
    const int kbase = z * 256;
    float* C = hp + (size_t)z * HP_STRIDE;
    const int tx = t & 15, ty = t >> 4;
    const int sr = t >> 3, sc = (t & 7) << 2;

    const float* Abase = A + (size_t)(m0 + sr) * Fdim + kbase + sc;
    const float* Wbase = W + (size_t)(n0 + sr) * Fdim + kbase + sc;
    float4 ra0, ra1, rb0, rb1;

    auto store_tile = [&](int buf) {
      Ash[buf][sc+0][sr] = ra0.x; Ash[buf][sc+1][sr] = ra0.y;
      Ash[buf][sc+2][sr] = ra0.z; Ash[buf][sc+3][sr] = ra0.w;
      Ash[buf][sc+0][sr+32] = ra1.x; Ash[buf][sc+1][sr+32] = ra1.y;
      Ash[buf][sc+2][sr+32] = ra1.z; Ash[buf][sc+3][sr+32] = ra1.w;
      Bsh[buf][sc+0][sr] = rb0.x; Bsh[buf][sc+1][sr] = rb0.y;
      Bsh[buf][sc+2][sr] = rb0.z; Bsh[buf][sc+3][sr] = rb0.w;
      Bsh[buf][sc+0][sr+32] = rb1.x; Bsh[buf][sc+1][sr+32] = rb1.y;
      Bsh[buf][sc+2][sr+32] = rb1.z; Bsh[buf][sc+3][sr+32] = rb1.w;
    };

    ra0 = *(const float4*)(Abase);
    ra1 = *(const float4*)(Abase + 32 * Fdim);
    rb0 = *(const float4*)(Wbase);
    rb1 = *(const float4*)(Wbase + 32 * Fdim);
    store_tile(0);
    __syncthreads();

    float acc4[4][4] = {};

    #pragma unroll
    for (int kc = 0; kc < 256; kc += 32) {
      const int cur = (kc >> 5) & 1;
      if (kc + 32 < 256) {
        ra0 = *(const float4*)(Abase + kc + 32);
        ra1 = *(const float4*)(Abase + kc + 32 + 32 * Fdim);
        rb0 = *(const float4*)(Wbase + kc + 32);
        rb1 = *(const float4*)(Wbase + kc + 32 + 32 * Fdim);
      }
      #pragma unroll 8
      for (int k = 0; k < 32; ++k) {
        float4 av = *(const float4*)&Ash[cur][k][ty << 2];
        float4 bv = *(const float4*)&Bsh[cur][k][tx << 2];
        acc4[0][0] = fmaf(av.x, bv.x, acc4[0][0]); acc4[0][1] = fmaf(av.x, bv.y, acc4[0][1]);
        acc4[0][2] = fmaf(av.x, bv.z, acc4[0][2]); acc4[0][3] = fmaf(av.x, bv.w, acc4[0][3]);
        acc4[1][0] = fmaf(av.y, bv.x, acc4[1][0]); acc4[1][1] = fmaf(av.y, bv.y, acc4[1][1]);
        acc4[1][2] = fmaf(av.y, bv.z, acc4[1][2]); acc4[1][3] = fmaf(av.y, bv.w, acc4[1][3]);
        acc4[2][0] = fmaf(av.z, bv.x, acc4[2][0]); acc4[2][1] = fmaf(av.z, bv.y, acc4[2][1]);
        acc4[2][2] = fmaf(av.z, bv.z, acc4[2][2]); acc4[2][3] = fmaf(av.z, bv.w, acc4[2][3]);
        acc4[3][0] = fmaf(av.w, bv.x, acc4[3][0]); acc4[3][1] = fmaf(av.w, bv.y, acc4[3][1]);
        acc4[3][2] = fmaf(av.w, bv.z, acc4[3][2]); acc4[3][3] = fmaf(av.w, bv.w, acc4[3][3]);
      }
      if (kc + 32 < 256) store_tile(cur ^ 1);
      __syncthreads();
    }

    float4 bi = make_float4(0.0f, 0.0f, 0.0f, 0.0f);
    if (z == 0) bi = *(const float4*)(bias + n0 + (tx << 2));
    #pragma unroll
    for (int i = 0; i < 4; ++i) {
      float4 o;
      o.x = acc4[i][0] + bi.x; o.y = acc4[i][1] + bi.y;
      o.z = acc4[i][2] + bi.z; o.w = acc4[i][3] + bi.w;
      *(float4*)(C + (size_t)(m0 + (ty << 2) + i) * Fdim + n0 + (tx << 2)) = o;
    }
  }

  // release: all stores issued (barrier) -> L2 writeback -> flag visible
  __syncthreads();
  if (t == 0) {
    __threadfence();
    __hip_atomic_store(&fcflag[bid], FLAG_MAGIC(bid),
                       __ATOMIC_RELEASE, __HIP_MEMORY_SCOPE_AGENT);
  }

  // ================= phase 2: score partial GEMM =================
  {
    // bid = sbx + 4*sby + 16*(b*4+kz)  (old grid (4,4,16))
    const int sbx = bid & 3, sby = (bid >> 2) & 3, sbz = bid >> 4;
    const int b = sbz >> 2, kz = sbz & 3;
    const int m0 = sbx * 64, n0 = sby * 64;
    const int kbase = kz * 128;

    // spin on the 8 fc producers of our A/B panels (lane-parallel)
    if (t < 8) {
      const int mi = (t & 1) ? (b * 4 + sby) : (b * 4 + sbx);
      const int ni = 2 * kz + ((t >> 1) & 1);
      const int zz = t >> 2;
      const int idx = mi + 16 * ni + 128 * zz;
      const unsigned long long want = FLAG_MAGIC(idx);
      while (__hip_atomic_load(&fcflag[idx], __ATOMIC_RELAXED,
                               __HIP_MEMORY_SCOPE_AGENT) != want) {}
    }
    __syncthreads();
    if (t == 0) __threadfence();  // invalidate L1/L2 before reading hp
    __syncthreads();

    const float* h0 = hp;
    const float* h1 = hp + HP_STRIDE;
    float* C = Sp + (size_t)kz * SP_STRIDE + (size_t)b * Pn * Pn;
    const size_t rb = (size_t)b * Pn;
    const int tx = t & 15, ty = t >> 4;
    const int sr = t >> 3, sc = (t & 7) << 2;
    const size_t aoff = (rb + m0 + sr) * Fdim + kbase + sc;
    const size_t boff = (rb + n0 + sr) * Fdim + kbase + sc;

    float4 la0, ha0, la1, ha1, lb0, hb0, lb1, hb1;

    auto load_tile = [&](int kc) {
      la0 = *(const float4*)(h0 + aoff + kc);
      ha0 = *(const float4*)(h1 + aoff + kc);
      la1 = *(const float4*)(h0 + aoff + kc + 32 * Fdim);
      ha1 = *(const float4*)(h1 + aoff + kc + 32 * Fdim);
      lb0 = *(const float4*)(h0 + boff + kc);
      hb0 = *(const float4*)(h1 + boff + kc);
      lb1 = *(const float4*)(h0 + boff + kc + 32 * Fdim);
      hb1 = *(const float4*)(h1 + boff + kc + 32 * Fdim);
    };
    auto store_tile = [&](int buf) {
      float4 a0, a1, b0v, b1v;
      a0.x = la0.x + ha0.x; a0.y = la0.y + ha0.y; a0.z = la0.z + ha0.z; a0.w = la0.w + ha0.w;
      a1.x = la1.x + ha1.x; a1.y = la1.y + ha1.y; a1.z = la1.z + ha1.z; a1.w = la1.w + ha1.w;
      b0v.x = lb0.x + hb0.x; b0v.y = lb0.y + hb0.y; b0v.z = lb0.z + hb0.z; b0v.w = lb0.w + hb0.w;
      b1v.x = lb1.x + hb1.x; b1v.y = lb1.y + hb1.y; b1v.z = lb1.z + hb1.z; b1v.w = lb1.w + hb1.w;
      Ash[buf][sc+0][sr] = a0.x; Ash[buf][sc+1][sr] = a0.y;
      Ash[buf][sc+2][sr] = a0.z; Ash[buf][sc+3][sr] = a0.w;
      Ash[buf][sc+0][sr+32] = a1.x; Ash[buf][sc+1][sr+32] = a1.y;
      Ash[buf][sc+2][sr+32] = a1.z; Ash[buf][sc+3][sr+32] = a1.w;
      Bsh[buf][sc+0][sr] = b0v.x; Bsh[buf][sc+1][sr] = b0v.y;
      Bsh[buf][sc+2][sr] = b0v.z; Bsh[buf][sc+3][sr] = b0v.w;
      Bsh[buf][sc+0][sr+32] = b1v.x; Bsh[buf][sc+1][sr+32] = b1v.y;
      Bsh[buf][sc+2][sr+32] = b1v.z; Bsh[buf][sc+3][sr+32] = b1v.w;
    };

    load_tile(0);
    store_tile(0);
    __syncthreads();

    float acc4[4][4] = {};

    #pragma unroll
    for (int kc = 0; kc < 128; kc += 32) {
      const int cur = (kc >> 5) & 1;
      if (kc + 32 < 128) load_tile(kc + 32);
      #pragma unroll 8
      for (int k = 0; k < 32; ++k) {
        float4 av = *(const float4*)&Ash[cur][k][ty << 2];
        float4 bv = *(const float4*)&Bsh[cur][k][tx << 2];
        acc4[0][0] = fmaf(av.x, bv.x, acc4[0][0]); acc4[0][1] = fmaf(av.x, bv.y, acc4[0][1]);
        acc4[0][2] = fmaf(av.x, bv.z, acc4[0][2]); acc4[0][3] = fmaf(av.x, bv.w, acc4[0][3]);
        acc4[1][0] = fmaf(av.y, bv.x, acc4[1][0]); acc4[1][1] = fmaf(av.y, bv.y, acc4[1][1]);
        acc4[1][2] = fmaf(av.y, bv.z, acc4[1][2]); acc4[1][3] = fmaf(av.y, bv.w, acc4[1][3]);
        acc4[2][0] = fmaf(av.z, bv.x, acc4[2][0]); acc4[2][1] = fmaf(av.z, bv.y, acc4[2][1]);
        acc4[2][2] = fmaf(av.z, bv.z, acc4[2][2]); acc4[2][3] = fmaf(av.z, bv.w, acc4[2][3]);
        acc4[3][0] = fmaf(av.w, bv.x, acc4[3][0]); acc4[3][1] = fmaf(av.w, bv.y, acc4[3][1]);
        acc4[3][2] = fmaf(av.w, bv.z, acc4[3][2]); acc4[3][3] = fmaf(av.w, bv.w, acc4[3][3]);
      }
      if (kc + 32 < 128) store_tile(cur ^ 1);
      __syncthreads();
    }

    #pragma unroll
    for (int i = 0; i < 4; ++i) {
      float4 o; o.x = acc4[i][0]; o.y = acc4[i][1]; o.z = acc4[i][2]; o.w = acc4[i][3];
      *(float4*)(C + (size_t)(m0 + (ty << 2) + i) * Pn + n0 + (tx << 2)) = o;
    }
    if (m0 == n0 && tx == ty) {
      #pragma unroll
      for (int i = 0; i < 4; ++i)
        dn[(size_t)kz * Mrows + rb + m0 + (ty << 2) + i] = acc4[i][i];
    }
  }

  __syncthreads();
  if (t == 0) {
    __threadfence();
    __hip_atomic_store(&scflag[bid], FLAG_MAGIC(bid),
                       __ATOMIC_RELEASE, __HIP_MEMORY_SCOPE_AGENT);
  }

  // ================= phase 3: loss =================
  {
    // wait for ALL 256 score blocks (1 flag per thread); transitively
    // orders after every fc block too (sig, dn, Sp all fresh after inv).
    {
      const unsigned long long want = FLAG_MAGIC(t);
      while (__hip_atomic_load(&scflag[t], __ATOMIC_RELAXED,
                               __HIP_MEMORY_SCOPE_AGENT) != want) {}
    }
    __syncthreads();
    if (t == 0) __threadfence();
    __syncthreads();

    const int b = bid >> 6, p0 = (bid & 63) * 4;
    const int q = t;
    const int w = q >> 6, lane = q & 63;
    const float* S0 = Sp + (size_t)b * Pn * Pn;
    const float* S1 = S0 + SP_STRIDE;
    const float* S2 = S0 + 2 * SP_STRIDE;
    const float* S3 = S0 + 3 * SP_STRIDE;

    {
      const int iq = (b << 8) + q;
      float d = dn[iq] + dn[Mrows + iq] + dn[2 * Mrows + iq] + dn[3 * Mrows + iq];
      invn[q] = 1.0f / fmaxf(sqrtf(d), 1e-12f);
    }
    __syncthreads();

    const int p = p0 + w;
    const int ro = p << 8;
    const ulonglong2 sp = sig[(b << 8) + p];
    const float ip = invn[p];

    float s[4];
    unsigned eqm = 0;
    #pragma unroll
    for (int c = 0; c < 4; ++c) {
      const int qq = (c << 6) + lane;
      float Sv = S0[ro + qq] + S1[ro + qq] + S2[ro + qq] + S3[ro + qq];
      s[c] = Sv * ip * invn[qq] * INV_TAU;
      bool eq;
      if (qq == p) eq = true;
      else {
        ulonglong2 sq = sig[(b << 8) + qq];
        if (sq.x == sp.x && sq.y == sp.y) {
          bool v = true;
          const float* lp = labels + (size_t)((b << 8) + p) * Fdim;
          const float* lq = labels + (size_t)((b << 8) + qq) * Fdim;
          for (int j = 0; j < Fdim; ++j) v = v && (lp[j] == lq[j]);
          eq = v;
        } else eq = false;
      }
      if (eq) eqm |= (1u << c);
    }

    float m = fmaxf(fmaxf(s[0], s[1]), fmaxf(s[2], s[3]));
    m = wave_max(m);

    float e[4], z = 0.0f, n = 0.0f;
    #pragma unroll
    for (int c = 0; c < 4; ++c) {
      e[c] = expf(s[c] - m);
      z += e[c];
      n += ((eqm >> c) & 1u) ? 1.0f : 0.0f;
    }
    z = wave_sum(z);
    n = wave_sum(n);

    float contrib = 0.0f;
    #pragma unroll
    for (int c = 0; c < 4; ++c) {
      if ((eqm >> c) & 1u) {
        float prob = fminf(fmaxf(e[c] / z, EPSC), 1.0f - EPSC);
        contrib += (-logf(n) - logf(prob)) / n;
      }
    }
    contrib = wave_sum(contrib);
    if (lane == 0) red[w] = contrib;
    __syncthreads();
    if (q == 0) {
      atomicAdd(acc, red[0] + red[1] + red[2] + red[3]);
      __threadfence();
      unsigned int v = atomicAdd(done, 1u);
      if (v == 255u) {
        float tot = atomicAdd(acc, 0.0f);
        out[0] = tot * (1.0f / (float)(Bz * Pn));
      }
    }
  }
}

extern "C" void kernel_launch(void* const* d_in, const int* in_sizes, int n_in,
                              void* d_out, int out_size, void* d_ws, size_t ws_size,
                              hipStream_t stream) {
  const float* inputs = (const float*)d_in[0];
  const float* labels = (const float*)d_in[1];
  const float* W      = (const float*)d_in[2];
  const float* bias   = (const float*)d_in[3];
  float* out = (float*)d_out;

  char* ws = (char*)d_ws;
  float* acc         = (float*)ws;                          // 4 B
  unsigned int* done = (unsigned int*)(ws + 4);             // 4 B
  float* hp = (float*)(ws + 256);                           // 2 * 2 MB fc partials
  float* Sp = (float*)(ws + 256 + 2 * HP_STRIDE * 4);       // 4 * 1 MB score partials
  ulonglong2* sig = (ulonglong2*)(ws + 256 + 2 * HP_STRIDE * 4 + 4 * SP_STRIDE * 4);
  char* after_sig = ws + 256 + 2 * HP_STRIDE * 4 + 4 * SP_STRIDE * 4
                    + (size_t)Mrows * sizeof(ulonglong2);
  float* dn = (float*)after_sig;                            // 4 * 1024 f32
  unsigned long long* fcflag = (unsigned long long*)(after_sig + 4 * Mrows * 4);
  unsigned long long* scflag = fcflag + 256;

  fused<<<256, 256, 0, stream>>>(inputs, W, bias, labels, hp, sig, Sp, dn,
                                 fcflag, scflag, acc, done, out);
}

// Round 4
// 95.097 us; speedup vs baseline: 1.3441x; 1.3441x over previous
//
#include <hip/hip_runtime.h>

// MaskPatchClassificationHead — B=4, P=256, F=512
// loss = KL(dist || softmax(x x^T / tau)) batchmean, x = normalize(inputs@W^T + b)
// 3-node graph: fc_sig (fc GEMM K-split2, 4x4 micro, dbuf LDS; label sigs; acc zero;
//                       bias folded into z==0 partial)
//            -> score_gemm (h h^T K-split4, 4x4 micro, dbuf LDS; writes diag partials dn)
//            -> loss (wave-per-row, butterfly-shuffle reductions, norms from dn)
// NOTE: single-kernel fusion with cross-block flags was tried and regressed 74 µs
// (per-XCD L2 writeback storms + agent-scope flag polling) — keep kernel boundaries.

#define INV_TAU (1.0f / 0.07f)
#define EPSC 1e-5f

constexpr int Bz = 4;
constexpr int Pn = 256;
constexpr int Fdim = 512;
constexpr int Mrows = Bz * Pn;                       // 1024
constexpr size_t HP_STRIDE = (size_t)Mrows * Fdim;   // per fc K-half partial
constexpr size_t SP_STRIDE = (size_t)Bz * Pn * Pn;   // per score K-quarter partial

// Butterfly reductions: result valid in ALL lanes (xor exchange), unlike
// __shfl_down which leaves the total only in lane 0.
__device__ __forceinline__ float wave_sum(float v) {
  #pragma unroll
  for (int o = 32; o > 0; o >>= 1) v += __shfl_xor(v, o, 64);
  return v;
}
__device__ __forceinline__ float wave_max(float v) {
  #pragma unroll
  for (int o = 32; o > 0; o >>= 1) v = fmaxf(v, __shfl_xor(v, o, 64));
  return v;
}
__device__ __forceinline__ unsigned long long mix64(unsigned long long z) {
  z ^= z >> 33; z *= 0xff51afd7ed558ccdULL;
  z ^= z >> 33; z *= 0xc4ceb9fe1a85ec53ULL;
  z ^= z >> 33; return z;
}

// ---------------- fc partial GEMM + label sigs + accumulator zeroing
// hp[z][m][n] = sum_{k in half z} A[m][k] W[n][k]  (+bias[n] folded into z==0)
// 64x64 tile, 4x4 micro, BK=32 double-buffered, 256 threads.
// grid (16, 8, 2) = 256 blocks (1/CU).
__global__ __launch_bounds__(256) void fc_sig(const float* __restrict__ A,
                                              const float* __restrict__ W,
                                              const float* __restrict__ bias,
                                              const float* __restrict__ labels,
                                              float* __restrict__ hp,
                                              ulonglong2* __restrict__ sig,
                                              float* __restrict__ acc,
                                              unsigned int* __restrict__ done) {
  const int t = threadIdx.x;
  const int bid = blockIdx.x + 16 * (blockIdx.y + 8 * blockIdx.z);
  if (bid == 0 && t == 0) { acc[0] = 0.0f; done[0] = 0u; }

  // --- label signatures: 4 rows per block, one 64-lane group per row
  {
    const int g = t >> 6, lane = t & 63;
    const int row = bid * 4 + g;
    const uint4* l4 = (const uint4*)(labels + (size_t)row * Fdim);
    unsigned long long h1 = 0, h2 = 0;
    #pragma unroll
    for (int c = lane; c < Fdim / 4; c += 64) {
      uint4 wv = l4[c];
      unsigned long long w01 = ((unsigned long long)wv.y << 32) | wv.x;
      unsigned long long w23 = ((unsigned long long)wv.w << 32) | wv.z;
      unsigned long long idx = (unsigned long long)c;
      h1 ^= mix64(w01 + idx * 0x9E3779B97F4A7C15ULL + 0x0123456789ABCDEFULL);
      h1 ^= mix64(w23 + idx * 0xC2B2AE3D27D4EB4FULL + 1ULL);
      h2 ^= mix64(w01 ^ (idx * 0x165667B19E3779F9ULL + 7ULL));
      h2 ^= mix64(w23 ^ (idx * 0x27D4EB2F165667C5ULL + 13ULL));
    }
    #pragma unroll
    for (int o = 32; o > 0; o >>= 1) {
      h1 ^= __shfl_down(h1, o, 64);
      h2 ^= __shfl_down(h2, o, 64);
    }
    if (lane == 0) { sig[row].x = h1; sig[row].y = h2; }
  }

  // --- fc GEMM
  const int m0 = blockIdx.x * 64, n0 = blockIdx.y * 64;
  const int kbase = blockIdx.z * 256;
  float* C = hp + (size_t)blockIdx.z * HP_STRIDE;
  __shared__ float Ash[2][32][68];  // [buf][k][m]
  __shared__ float Bsh[2][32][68];  // [buf][k][n]
  const int tx = t & 15, ty = t >> 4;            // out: rows ty*4+i, cols tx*4+j
  const int sr = t >> 3, sc = (t & 7) << 2;      // stage: rows sr, sr+32; k-cols sc..sc+3

  const float* Abase = A + (size_t)(m0 + sr) * Fdim + kbase + sc;
  const float* Wbase = W + (size_t)(n0 + sr) * Fdim + kbase + sc;
  float4 ra0, ra1, rb0, rb1;

  auto store_tile = [&](int buf) {
    Ash[buf][sc+0][sr] = ra0.x; Ash[buf][sc+1][sr] = ra0.y;
    Ash[buf][sc+2][sr] = ra0.z; Ash[buf][sc+3][sr] = ra0.w;
    Ash[buf][sc+0][sr+32] = ra1.x; Ash[buf][sc+1][sr+32] = ra1.y;
    Ash[buf][sc+2][sr+32] = ra1.z; Ash[buf][sc+3][sr+32] = ra1.w;
    Bsh[buf][sc+0][sr] = rb0.x; Bsh[buf][sc+1][sr] = rb0.y;
    Bsh[buf][sc+2][sr] = rb0.z; Bsh[buf][sc+3][sr] = rb0.w;
    Bsh[buf][sc+0][sr+32] = rb1.x; Bsh[buf][sc+1][sr+32] = rb1.y;
    Bsh[buf][sc+2][sr+32] = rb1.z; Bsh[buf][sc+3][sr+32] = rb1.w;
  };

  // prologue: stage kc=0
  ra0 = *(const float4*)(Abase);
  ra1 = *(const float4*)(Abase + 32 * Fdim);
  rb0 = *(const float4*)(Wbase);
  rb1 = *(const float4*)(Wbase + 32 * Fdim);
  store_tile(0);
  __syncthreads();

  float acc4[4][4] = {};

  #pragma unroll
  for (int kc = 0; kc < 256; kc += 32) {
    const int cur = (kc >> 5) & 1;
    if (kc + 32 < 256) {  // prefetch next K-step into registers
      ra0 = *(const float4*)(Abase + kc + 32);
      ra1 = *(const float4*)(Abase + kc + 32 + 32 * Fdim);
      rb0 = *(const float4*)(Wbase + kc + 32);
      rb1 = *(const float4*)(Wbase + kc + 32 + 32 * Fdim);
    }
    #pragma unroll 8
    for (int k = 0; k < 32; ++k) {
      float4 av = *(const float4*)&Ash[cur][k][ty << 2];
      float4 bv = *(const float4*)&Bsh[cur][k][tx << 2];
      acc4[0][0] = fmaf(av.x, bv.x, acc4[0][0]); acc4[0][1] = fmaf(av.x, bv.y, acc4[0][1]);
      acc4[0][2] = fmaf(av.x, bv.z, acc4[0][2]); acc4[0][3] = fmaf(av.x, bv.w, acc4[0][3]);
      acc4[1][0] = fmaf(av.y, bv.x, acc4[1][0]); acc4[1][1] = fmaf(av.y, bv.y, acc4[1][1]);
      acc4[1][2] = fmaf(av.y, bv.z, acc4[1][2]); acc4[1][3] = fmaf(av.y, bv.w, acc4[1][3]);
      acc4[2][0] = fmaf(av.z, bv.x, acc4[2][0]); acc4[2][1] = fmaf(av.z, bv.y, acc4[2][1]);
      acc4[2][2] = fmaf(av.z, bv.z, acc4[2][2]); acc4[2][3] = fmaf(av.z, bv.w, acc4[2][3]);
      acc4[3][0] = fmaf(av.w, bv.x, acc4[3][0]); acc4[3][1] = fmaf(av.w, bv.y, acc4[3][1]);
      acc4[3][2] = fmaf(av.w, bv.z, acc4[3][2]); acc4[3][3] = fmaf(av.w, bv.w, acc4[3][3]);
    }
    if (kc + 32 < 256) store_tile(cur ^ 1);
    __syncthreads();
  }

  // epilogue: z==0 partial carries the bias
  float4 bi = make_float4(0.0f, 0.0f, 0.0f, 0.0f);
  if (blockIdx.z == 0) bi = *(const float4*)(bias + n0 + (tx << 2));
  #pragma unroll
  for (int i = 0; i < 4; ++i) {
    float4 o;
    o.x = acc4[i][0] + bi.x; o.y = acc4[i][1] + bi.y;
    o.z = acc4[i][2] + bi.z; o.w = acc4[i][3] + bi.w;
    *(float4*)(C + (size_t)(m0 + (ty << 2) + i) * Fdim + n0 + (tx << 2)) = o;
  }
}

// ---------------- scores partial GEMM: Sp[kz][b][p][q], K-quarter kz of
// h[b*256+m][o] = hp0 + hp1 (bias already in hp0). 64x64 tile, 4x4 micro,
// BK=32 double-buffered, 256 threads. grid (4, 4, 16 = b*4+kz) = 256 blocks.
// Diagonal blocks also write dn[kz][b*256+p] = partial S_pp (for norms).
__global__ __launch_bounds__(256) void score_gemm(const float* __restrict__ hp,
                                                  float* __restrict__ Sp,
                                                  float* __restrict__ dn) {
  const int b = blockIdx.z >> 2, kz = blockIdx.z & 3;
  const int kbase = kz * 128;
  const int m0 = blockIdx.x * 64, n0 = blockIdx.y * 64;
  const float* h0 = hp;
  const float* h1 = hp + HP_STRIDE;
  float* C = Sp + (size_t)kz * SP_STRIDE + (size_t)b * Pn * Pn;
  const size_t rb = (size_t)b * Pn;
  __shared__ float Ash[2][32][68];
  __shared__ float Bsh[2][32][68];
  const int t = threadIdx.x, tx = t & 15, ty = t >> 4;
  const int sr = t >> 3, sc = (t & 7) << 2;
  const size_t aoff = (rb + m0 + sr) * Fdim + kbase + sc;
  const size_t boff = (rb + n0 + sr) * Fdim + kbase + sc;

  float4 la0, ha0, la1, ha1, lb0, hb0, lb1, hb1;

  auto load_tile = [&](int kc) {
    la0 = *(const float4*)(h0 + aoff + kc);
    ha0 = *(const float4*)(h1 + aoff + kc);
    la1 = *(const float4*)(h0 + aoff + kc + 32 * Fdim);
    ha1 = *(const float4*)(h1 + aoff + kc + 32 * Fdim);
    lb0 = *(const float4*)(h0 + boff + kc);
    hb0 = *(const float4*)(h1 + boff + kc);
    lb1 = *(const float4*)(h0 + boff + kc + 32 * Fdim);
    hb1 = *(const float4*)(h1 + boff + kc + 32 * Fdim);
  };
  auto store_tile = [&](int buf) {
    float4 a0, a1, b0v, b1v;
    a0.x = la0.x + ha0.x; a0.y = la0.y + ha0.y; a0.z = la0.z + ha0.z; a0.w = la0.w + ha0.w;
    a1.x = la1.x + ha1.x; a1.y = la1.y + ha1.y; a1.z = la1.z + ha1.z; a1.w = la1.w + ha1.w;
    b0v.x = lb0.x + hb0.x; b0v.y = lb0.y + hb0.y; b0v.z = lb0.z + hb0.z; b0v.w = lb0.w + hb0.w;
    b1v.x = lb1.x + hb1.x; b1v.y = lb1.y + hb1.y; b1v.z = lb1.z + hb1.z; b1v.w = lb1.w + hb1.w;
    Ash[buf][sc+0][sr] = a0.x; Ash[buf][sc+1][sr] = a0.y;
    Ash[buf][sc+2][sr] = a0.z; Ash[buf][sc+3][sr] = a0.w;
    Ash[buf][sc+0][sr+32] = a1.x; Ash[buf][sc+1][sr+32] = a1.y;
    Ash[buf][sc+2][sr+32] = a1.z; Ash[buf][sc+3][sr+32] = a1.w;
    Bsh[buf][sc+0][sr] = b0v.x; Bsh[buf][sc+1][sr] = b0v.y;
    Bsh[buf][sc+2][sr] = b0v.z; Bsh[buf][sc+3][sr] = b0v.w;
    Bsh[buf][sc+0][sr+32] = b1v.x; Bsh[buf][sc+1][sr+32] = b1v.y;
    Bsh[buf][sc+2][sr+32] = b1v.z; Bsh[buf][sc+3][sr+32] = b1v.w;
  };

  load_tile(0);
  store_tile(0);
  __syncthreads();

  float acc4[4][4] = {};

  #pragma unroll
  for (int kc = 0; kc < 128; kc += 32) {
    const int cur = (kc >> 5) & 1;
    if (kc + 32 < 128) load_tile(kc + 32);
    #pragma unroll 8
    for (int k = 0; k < 32; ++k) {
      float4 av = *(const float4*)&Ash[cur][k][ty << 2];
      float4 bv = *(const float4*)&Bsh[cur][k][tx << 2];
      acc4[0][0] = fmaf(av.x, bv.x, acc4[0][0]); acc4[0][1] = fmaf(av.x, bv.y, acc4[0][1]);
      acc4[0][2] = fmaf(av.x, bv.z, acc4[0][2]); acc4[0][3] = fmaf(av.x, bv.w, acc4[0][3]);
      acc4[1][0] = fmaf(av.y, bv.x, acc4[1][0]); acc4[1][1] = fmaf(av.y, bv.y, acc4[1][1]);
      acc4[1][2] = fmaf(av.y, bv.z, acc4[1][2]); acc4[1][3] = fmaf(av.y, bv.w, acc4[1][3]);
      acc4[2][0] = fmaf(av.z, bv.x, acc4[2][0]); acc4[2][1] = fmaf(av.z, bv.y, acc4[2][1]);
      acc4[2][2] = fmaf(av.z, bv.z, acc4[2][2]); acc4[2][3] = fmaf(av.z, bv.w, acc4[2][3]);
      acc4[3][0] = fmaf(av.w, bv.x, acc4[3][0]); acc4[3][1] = fmaf(av.w, bv.y, acc4[3][1]);
      acc4[3][2] = fmaf(av.w, bv.z, acc4[3][2]); acc4[3][3] = fmaf(av.w, bv.w, acc4[3][3]);
    }
    if (kc + 32 < 128) store_tile(cur ^ 1);
    __syncthreads();
  }

  #pragma unroll
  for (int i = 0; i < 4; ++i) {
    float4 o; o.x = acc4[i][0]; o.y = acc4[i][1]; o.z = acc4[i][2]; o.w = acc4[i][3];
    *(float4*)(C + (size_t)(m0 + (ty << 2) + i) * Pn + n0 + (tx << 2)) = o;
  }
  // diagonal partials for norms (coalesced-enough tiny writes)
  if (m0 == n0 && tx == ty) {
    #pragma unroll
    for (int i = 0; i < 4; ++i)
      dn[(size_t)kz * Mrows + rb + m0 + (ty << 2) + i] = acc4[i][i];
  }
}

// ---------------- loss: 256 blocks x 256 thr; block = (batch b, 4 rows).
// One wave fully owns one row: 256 q in 4 reg-resident chunks, butterfly
// shuffle reductions (result in all lanes). Norms from dn partials.
__global__ __launch_bounds__(256) void loss_kernel(const float* __restrict__ Sp,
                                                   const ulonglong2* __restrict__ sig,
                                                   const float* __restrict__ labels,
                                                   const float* __restrict__ dn,
                                                   float* __restrict__ acc,
                                                   unsigned int* __restrict__ done,
                                                   float* __restrict__ out) {
  const int bx = blockIdx.x;
  const int b = bx >> 6, p0 = (bx & 63) * 4;
  const int q = threadIdx.x;
  const int w = q >> 6, lane = q & 63;
  __shared__ float invn[256];
  __shared__ float red[4];
  const float* S0 = Sp + (size_t)b * Pn * Pn;
  const float* S1 = S0 + SP_STRIDE;
  const float* S2 = S0 + 2 * SP_STRIDE;
  const float* S3 = S0 + 3 * SP_STRIDE;

  // diagonal norms from dn partials (coalesced)
  {
    const int iq = (b << 8) + q;
    float d = dn[iq] + dn[Mrows + iq] + dn[2 * Mrows + iq] + dn[3 * Mrows + iq];
    invn[q] = 1.0f / fmaxf(sqrtf(d), 1e-12f);
  }
  __syncthreads();

  const int p = p0 + w;
  const int ro = p << 8;
  const ulonglong2 sp = sig[(b << 8) + p];
  const float ip = invn[p];

  float s[4];
  unsigned eqm = 0;
  #pragma unroll
  for (int c = 0; c < 4; ++c) {
    const int qq = (c << 6) + lane;
    float Sv = S0[ro + qq] + S1[ro + qq] + S2[ro + qq] + S3[ro + qq];
    s[c] = Sv * ip * invn[qq] * INV_TAU;
    // equality: exact row equality <=> L1 dist == 0. sig mismatch => unequal;
    // sig match with q!=p => exact verify (cold path).
    bool eq;
    if (qq == p) eq = true;
    else {
      ulonglong2 sq = sig[(b << 8) + qq];
      if (sq.x == sp.x && sq.y == sp.y) {
        bool v = true;
        const float* lp = labels + (size_t)((b << 8) + p) * Fdim;
        const float* lq = labels + (size_t)((b << 8) + qq) * Fdim;
        for (int j = 0; j < Fdim; ++j) v = v && (lp[j] == lq[j]);
        eq = v;
      } else eq = false;
    }
    if (eq) eqm |= (1u << c);
  }

  float m = fmaxf(fmaxf(s[0], s[1]), fmaxf(s[2], s[3]));
  m = wave_max(m);  // broadcast to all lanes (xor butterfly)

  float e[4], z = 0.0f, n = 0.0f;
  #pragma unroll
  for (int c = 0; c < 4; ++c) {
    e[c] = expf(s[c] - m);
    z += e[c];
    n += ((eqm >> c) & 1u) ? 1.0f : 0.0f;
  }
  z = wave_sum(z);  // broadcast
  n = wave_sum(n);  // broadcast

  float contrib = 0.0f;
  #pragma unroll
  for (int c = 0; c < 4; ++c) {
    if ((eqm >> c) & 1u) {
      float prob = fminf(fmaxf(e[c] / z, EPSC), 1.0f - EPSC);
      contrib += (-logf(n) - logf(prob)) / n;
    }
  }
  contrib = wave_sum(contrib);
  if (lane == 0) red[w] = contrib;
  __syncthreads();
  if (q == 0) {
    atomicAdd(acc, red[0] + red[1] + red[2] + red[3]);
    __threadfence();
    unsigned int v = atomicAdd(done, 1u);
    if (v == 255u) {  // last of 256 blocks: all acc adds visible
      float tot = atomicAdd(acc, 0.0f);
      out[0] = tot * (1.0f / (float)(Bz * Pn));
    }
  }
}

extern "C" void kernel_launch(void* const* d_in, const int* in_sizes, int n_in,
                              void* d_out, int out_size, void* d_ws, size_t ws_size,
                              hipStream_t stream) {
  const float* inputs = (const float*)d_in[0];
  const float* labels = (const float*)d_in[1];
  const float* W      = (const float*)d_in[2];
  const float* bias   = (const float*)d_in[3];
  float* out = (float*)d_out;

  char* ws = (char*)d_ws;
  float* acc         = (float*)ws;                    // 4 B
  unsigned int* done = (unsigned int*)(ws + 4);       // 4 B
  float* hp = (float*)(ws + 256);                     // 2 * 2 MB fc partials
  float* Sp = (float*)(ws + 256 + 2 * HP_STRIDE * 4); // 4 * 1 MB score partials
  ulonglong2* sig = (ulonglong2*)(ws + 256 + 2 * HP_STRIDE * 4 + 4 * SP_STRIDE * 4);
  float* dn = (float*)(ws + 256 + 2 * HP_STRIDE * 4 + 4 * SP_STRIDE * 4
                       + (size_t)Mrows * sizeof(ulonglong2));  // 4 * 1024 diag partials

  fc_sig<<<dim3(16, 8, 2), 256, 0, stream>>>(inputs, W, bias, labels, hp, sig, acc, done);
  score_gemm<<<dim3(4, 4, 16), 256, 0, stream>>>(hp, Sp, dn);
  loss_kernel<<<256, 256, 0, stream>>>(Sp, sig, labels, dn, acc, done, out);
}